// Round 3
// baseline (283.151 us; speedup 1.0000x reference)
//
#include <hip/hip_runtime.h>

#define NBATCH  16
#define NSTRIPS 16                 // 64-column strips across 1024 cols
#define SEGROWS 64                 // rows per wave segment
#define NSEGS   (1024 / SEGROWS)   // 16
#define NWAVES  (NBATCH * NSEGS * NSTRIPS)  // 4096 waves
#define NBLOCKS (NWAVES / 4)       // 1024 blocks x 4 waves = 4 blocks/CU exactly
#define NHIST   8                  // global histogram copies

__device__ __forceinline__ float gray3(float r, float g, float b) {
    return (r * 0.299f + g * 0.587f) + b * 0.114f;
}

__global__ __launch_bounds__(256) void lbp_hist_kernel(
        const float* __restrict__ img, unsigned* __restrict__ g_hist) {
    __shared__ unsigned s_hist[4][256];               // one copy per wave
    const int tid  = threadIdx.x;
    const int wv   = tid >> 6;
    const int lane = tid & 63;
    #pragma unroll
    for (int i = 0; i < 4; ++i) s_hist[i][tid] = 0u;
    __syncthreads();

    const int w     = blockIdx.x * 4 + wv;            // flat wave id 0..4095
    const int strip = w & (NSTRIPS - 1);              // adjacent strips share halo cols in L2
    const int seg   = (w >> 4) & (NSEGS - 1);
    const int b     = w >> 8;
    const int wx    = strip << 6;
    const int x     = wx + lane;
    const int y0    = seg * SEGROWS;
    const int ylast = y0 + SEGROWS;                   // deepest row consumed (y0+64)

    const float* R = img + (size_t)b * 3145728u;
    const float* G = R + 1048576;
    const float* B = R + 2097152;

    const bool hL  = (lane == 0);
    const bool hR  = (lane == 63);
    const int  hx  = hL ? (wx - 1) : (wx + 64);
    const bool hOk = (hL || hR) && ((unsigned)hx < 1024u);

    // issue: start loads for one image row; zero-fill OOB rows (SAME zero padding)
    // and rows beyond [y0-1, y0+64] (clamp avoids 2 wasted prefetch rows/wave).
    auto issue = [&](int y, float& rr, float& gg, float& bb,
                     float& hr2, float& hg2, float& hb2) {
        rr = gg = bb = hr2 = hg2 = hb2 = 0.f;
        if ((unsigned)y < 1024u && y <= ylast) {      // wave-uniform guard
            const int o = y << 10;
            rr = R[o + x]; gg = G[o + x]; bb = B[o + x];
            if (hOk) { hr2 = R[o + hx]; hg2 = G[o + hx]; hb2 = B[o + hx]; }
        }
    };
    // finish: gray-convert a landed row and resolve left/center/right via shfl,
    // patching lanes 0/63 with the dedicated halo-column values.
    auto finish = [&](float rr, float gg, float bb, float hr2, float hg2, float hb2,
                      float& l, float& c, float& r) {
        const float cc = gray3(rr, gg, bb);
        const float hh = gray3(hr2, hg2, hb2);        // meaningful only on lanes 0/63
        l = __shfl_up(cc, 1);
        r = __shfl_down(cc, 1);
        if (hL) l = hh;                               // column wx-1 (0 at image edge)
        if (hR) r = hh;                               // column wx+64 (0 at image edge)
        c = cc;
    };

    // rolling 3x3 window: r0 = row y-1, r1 = row y, r2 = row y+1 (for pixel row y)
    float r0l, r0c, r0r, r1l, r1c, r1r, r2l, r2c, r2r;
    // depth-2 prefetch: p1 = next row to be consumed (y+1), p2 = row y+2.
    // Rotation period 2 matches unroll 4 -> copies SSA-resolve, no early waitcnt.
    float p1r, p1g, p1b, p1hr, p1hg, p1hb;
    float p2r, p2g, p2b, p2hr, p2hg, p2hb;
    float nr,  ng,  nb,  nhr,  nhg,  nhb;

    issue(y0 - 1, p1r, p1g, p1b, p1hr, p1hg, p1hb);
    finish(p1r, p1g, p1b, p1hr, p1hg, p1hb, r0l, r0c, r0r);   // r0 = row y0-1
    issue(y0,     p1r, p1g, p1b, p1hr, p1hg, p1hb);
    finish(p1r, p1g, p1b, p1hr, p1hg, p1hb, r1l, r1c, r1r);   // r1 = row y0
    issue(y0 + 1, p1r, p1g, p1b, p1hr, p1hg, p1hb);           // p1 = row y0+1 in flight
    issue(y0 + 2, p2r, p2g, p2b, p2hr, p2hg, p2hb);           // p2 = row y0+2 in flight

    unsigned cnt0 = 0u, cnt255 = 0u;

    #pragma unroll 4
    for (int y = y0; y < y0 + SEGROWS; ++y) {
        // keep 2 rows of loads in flight: issue y+3 before waiting on y+1
        issue(y + 3, nr, ng, nb, nhr, nhg, nhb);
        finish(p1r, p1g, p1b, p1hr, p1hg, p1hb, r2l, r2c, r2r);  // r2 = row y+1

        const unsigned code =
            (r0r >= r1c ?   1u : 0u) |   // (y-1, x+1)
            (r1r >= r1c ?   2u : 0u) |   // (y,   x+1)
            (r2r >= r1c ?   4u : 0u) |   // (y+1, x+1)
            (r2c >= r1c ?   8u : 0u) |   // (y+1, x  )
            (r2l >= r1c ?  16u : 0u) |   // (y+1, x-1)
            (r1l >= r1c ?  32u : 0u) |   // (y,   x-1)
            (r0l >= r1c ?  64u : 0u) |   // (y-1, x-1)
            (r0c >= r1c ? 128u : 0u);    // (y-1, x  )

        // hot bins (center is 3x3 extremum, ~11% each on uniform data): ballot, no atomic
        cnt0   += (unsigned)__popcll(__ballot(code ==   0u));
        cnt255 += (unsigned)__popcll(__ballot(code == 255u));
        if ((code - 1u) < 254u)                       // codes 1..254: near-uniform, low conflict
            atomicAdd(&s_hist[wv][code], 1u);

        r0l = r1l; r0c = r1c; r0r = r1r;              // computed values: cheap v_movs
        r1l = r2l; r1c = r2c; r1r = r2r;
        p1r = p2r; p1g = p2g; p1b = p2b; p1hr = p2hr; p1hg = p2hg; p1hb = p2hb;
        p2r = nr;  p2g = ng;  p2b = nb;  p2hr = nhr;  p2hg = nhg;  p2hb = nhb;
    }

    if (lane == 0) {                                  // cnt0/cnt255 are wave-uniform
        atomicAdd(&s_hist[wv][0],   cnt0);
        atomicAdd(&s_hist[wv][255], cnt255);
    }
    __syncthreads();
    const unsigned total = s_hist[0][tid] + s_hist[1][tid] + s_hist[2][tid] + s_hist[3][tid];
    atomicAdd(&g_hist[((blockIdx.x & (NHIST - 1)) << 8) + tid], total);
}

__global__ __launch_bounds__(256) void lbp_finalize(
        const unsigned* __restrict__ g_hist, float* __restrict__ out) {
    __shared__ float red[256];
    const int i = threadIdx.x;
    unsigned hv = 0u;
    #pragma unroll
    for (int c = 0; c < NHIST; ++c) hv += g_hist[(c << 8) + i];
    const float h = (float)hv;
    red[i] = h;
    __syncthreads();
    #pragma unroll
    for (int s = 128; s > 0; s >>= 1) {
        if (i < s) red[i] += red[i + s];
        __syncthreads();
    }
    const float mean = red[0] * (1.0f / 256.0f);
    __syncthreads();
    const float d = h - mean;
    red[i] = d * d;
    __syncthreads();
    #pragma unroll
    for (int s = 128; s > 0; s >>= 1) {
        if (i < s) red[i] += red[i + s];
        __syncthreads();
    }
    const float stdv = sqrtf(red[0] * (1.0f / 255.0f));
    out[i] = d / stdv;
}

extern "C" void kernel_launch(void* const* d_in, const int* in_sizes, int n_in,
                              void* d_out, int out_size, void* d_ws, size_t ws_size,
                              hipStream_t stream) {
    const float* img = (const float*)d_in[0];
    unsigned* g_hist = (unsigned*)d_ws;   // NHIST * 256 * 4 = 8 KB scratch
    float* out = (float*)d_out;

    // graph-capture-safe stream memset (replaces a dedicated zeroing kernel launch)
    hipMemsetAsync(g_hist, 0, NHIST * 256 * sizeof(unsigned), stream);
    lbp_hist_kernel<<<NBLOCKS, 256, 0, stream>>>(img, g_hist);
    lbp_finalize<<<1, 256, 0, stream>>>(g_hist, out);
}

// Round 4
// 283.020 us; speedup vs baseline: 1.0005x; 1.0005x over previous
//
#include <hip/hip_runtime.h>

#define NBATCH  16
#define COLS_W  128                // columns per wave strip (64 lanes x float2)
#define NSTRIPS (1024 / COLS_W)    // 8
#define SEGROWS 32                 // rows per wave segment
#define NSEGS   (1024 / SEGROWS)   // 32
#define NWAVES  (NBATCH * NSEGS * NSTRIPS)  // 4096 waves
#define NBLOCKS (NWAVES / 4)       // 1024 blocks x 4 waves = 4 blocks/CU, 16 waves/CU
#define NHIST   8                  // global histogram copies

__device__ __forceinline__ float gray3(float r, float g, float b) {
    return (r * 0.299f + g * 0.587f) + b * 0.114f;
}

__global__ __launch_bounds__(256, 4) void lbp_hist_kernel(
        const float* __restrict__ img, unsigned* __restrict__ g_hist) {
    __shared__ unsigned s_hist[4][256];               // one copy per wave
    const int tid  = threadIdx.x;
    const int wv   = tid >> 6;
    const int lane = tid & 63;
    #pragma unroll
    for (int i = 0; i < 4; ++i) s_hist[i][tid] = 0u;
    __syncthreads();

    const int w     = blockIdx.x * 4 + wv;            // flat wave id 0..4095
    const int strip = w & (NSTRIPS - 1);              // adjacent waves -> adjacent strips (L2 halo hits)
    const int seg   = (w >> 3) & (NSEGS - 1);
    const int b     = w >> 8;
    const int wx    = strip * COLS_W;
    const int x     = wx + 2 * lane;                  // first of this lane's 2 columns (8B aligned)
    const int y0    = seg * SEGROWS;
    const int ylast = y0 + SEGROWS;                   // deepest row consumed (y0+32)

    const float* R = img + (size_t)b * 3145728u;
    const float* G = R + 1048576;
    const float* B = R + 2097152;

    const bool hL  = (lane == 0);
    const bool hR  = (lane == 63);
    const int  hx  = hL ? (wx - 1) : (wx + COLS_W);   // halo column for edge lanes
    const bool hOk = (hL || hR) && ((unsigned)hx < 1024u);

    // issue: start float2 loads for one image row; zero-fill OOB rows (SAME padding)
    // and rows beyond [y0-1, y0+32] (clamp avoids wasted prefetch rows).
    auto issue = [&](int y, float2& rr, float2& gg, float2& bb,
                     float& hr2, float& hg2, float& hb2) {
        rr = gg = bb = make_float2(0.f, 0.f);
        hr2 = hg2 = hb2 = 0.f;
        if ((unsigned)y < 1024u && y <= ylast) {      // wave-uniform guard
            const int o = y << 10;
            rr = *(const float2*)(R + o + x);
            gg = *(const float2*)(G + o + x);
            bb = *(const float2*)(B + o + x);
            if (hOk) { hr2 = R[o + hx]; hg2 = G[o + hx]; hb2 = B[o + hx]; }
        }
    };
    // finish: gray-convert a landed row; l = left-of-pixel0, r = right-of-pixel1.
    auto finish = [&](float2 rr, float2 gg, float2 bb, float hr2, float hg2, float hb2,
                      float& l, float& c0, float& c1, float& r) {
        c0 = gray3(rr.x, gg.x, bb.x);
        c1 = gray3(rr.y, gg.y, bb.y);
        const float hh = gray3(hr2, hg2, hb2);        // meaningful only on lanes 0/63
        const float lu = __shfl_up(c1, 1);            // lane-1's col 2l-1
        const float rd = __shfl_down(c0, 1);          // lane+1's col 2l+2
        l = hL ? hh : lu;                             // col x-1 (0-pad at image edge)
        r = hR ? hh : rd;                             // col x+2 (0-pad at image edge)
    };

    // rolling 3x3 window over 2-pixel groups: row k holds (l, c0, c1, r)
    float r0l, r0c0, r0c1, r0r;                       // row y-1
    float r1l, r1c0, r1c1, r1r;                       // row y
    float r2l, r2c0, r2c1, r2r;                       // row y+1
    // depth-2 prefetch: p1 = next consumed row, p2 = row after
    float2 p1r, p1g, p1b;  float p1hr, p1hg, p1hb;
    float2 p2r, p2g, p2b;  float p2hr, p2hg, p2hb;
    float2 nr,  ng,  nb;   float nhr,  nhg,  nhb;

    issue(y0 - 1, p1r, p1g, p1b, p1hr, p1hg, p1hb);
    finish(p1r, p1g, p1b, p1hr, p1hg, p1hb, r0l, r0c0, r0c1, r0r);   // row y0-1
    issue(y0,     p1r, p1g, p1b, p1hr, p1hg, p1hb);
    finish(p1r, p1g, p1b, p1hr, p1hg, p1hb, r1l, r1c0, r1c1, r1r);   // row y0
    issue(y0 + 1, p1r, p1g, p1b, p1hr, p1hg, p1hb);   // p1 = row y0+1 in flight
    issue(y0 + 2, p2r, p2g, p2b, p2hr, p2hg, p2hb);   // p2 = row y0+2 in flight

    unsigned cnt0 = 0u, cnt255 = 0u;

    #pragma unroll 4
    for (int y = y0; y < y0 + SEGROWS; ++y) {
        // keep 2 rows of loads in flight: issue y+3 before waiting on y+1
        issue(y + 3, nr, ng, nb, nhr, nhg, nhb);
        finish(p1r, p1g, p1b, p1hr, p1hg, p1hb, r2l, r2c0, r2c1, r2r);  // row y+1

        // pixel0 (col x): neighbors l | c0 | c1 per row, center r1c0
        const unsigned code0 =
            (r0c1 >= r1c0 ?   1u : 0u) |   // (y-1, x+1)
            (r1c1 >= r1c0 ?   2u : 0u) |   // (y,   x+1)
            (r2c1 >= r1c0 ?   4u : 0u) |   // (y+1, x+1)
            (r2c0 >= r1c0 ?   8u : 0u) |   // (y+1, x  )
            (r2l  >= r1c0 ?  16u : 0u) |   // (y+1, x-1)
            (r1l  >= r1c0 ?  32u : 0u) |   // (y,   x-1)
            (r0l  >= r1c0 ?  64u : 0u) |   // (y-1, x-1)
            (r0c0 >= r1c0 ? 128u : 0u);    // (y-1, x  )
        // pixel1 (col x+1): neighbors c0 | c1 | r per row, center r1c1
        const unsigned code1 =
            (r0r  >= r1c1 ?   1u : 0u) |
            (r1r  >= r1c1 ?   2u : 0u) |
            (r2r  >= r1c1 ?   4u : 0u) |
            (r2c1 >= r1c1 ?   8u : 0u) |
            (r2c0 >= r1c1 ?  16u : 0u) |
            (r1c0 >= r1c1 ?  32u : 0u) |
            (r0c0 >= r1c1 ?  64u : 0u) |
            (r0c1 >= r1c1 ? 128u : 0u);

        // hot bins (3x3 extremum, ~11% each on uniform data): ballot, no atomic
        cnt0   += (unsigned)__popcll(__ballot(code0 ==   0u));
        cnt0   += (unsigned)__popcll(__ballot(code1 ==   0u));
        cnt255 += (unsigned)__popcll(__ballot(code0 == 255u));
        cnt255 += (unsigned)__popcll(__ballot(code1 == 255u));
        if ((code0 - 1u) < 254u) atomicAdd(&s_hist[wv][code0], 1u);
        if ((code1 - 1u) < 254u) atomicAdd(&s_hist[wv][code1], 1u);

        r0l = r1l; r0c0 = r1c0; r0c1 = r1c1; r0r = r1r;
        r1l = r2l; r1c0 = r2c0; r1c1 = r2c1; r1r = r2r;
        p1r = p2r; p1g = p2g; p1b = p2b; p1hr = p2hr; p1hg = p2hg; p1hb = p2hb;
        p2r = nr;  p2g = ng;  p2b = nb;  p2hr = nhr;  p2hg = nhg;  p2hb = nhb;
    }

    if (lane == 0) {                                  // cnt0/cnt255 are wave-uniform
        atomicAdd(&s_hist[wv][0],   cnt0);
        atomicAdd(&s_hist[wv][255], cnt255);
    }
    __syncthreads();
    const unsigned total = s_hist[0][tid] + s_hist[1][tid] + s_hist[2][tid] + s_hist[3][tid];
    atomicAdd(&g_hist[((blockIdx.x & (NHIST - 1)) << 8) + tid], total);
}

__global__ __launch_bounds__(256) void lbp_finalize(
        const unsigned* __restrict__ g_hist, float* __restrict__ out) {
    __shared__ float red[256];
    const int i = threadIdx.x;
    unsigned hv = 0u;
    #pragma unroll
    for (int c = 0; c < NHIST; ++c) hv += g_hist[(c << 8) + i];
    const float h = (float)hv;
    red[i] = h;
    __syncthreads();
    #pragma unroll
    for (int s = 128; s > 0; s >>= 1) {
        if (i < s) red[i] += red[i + s];
        __syncthreads();
    }
    const float mean = red[0] * (1.0f / 256.0f);
    __syncthreads();
    const float d = h - mean;
    red[i] = d * d;
    __syncthreads();
    #pragma unroll
    for (int s = 128; s > 0; s >>= 1) {
        if (i < s) red[i] += red[i + s];
        __syncthreads();
    }
    const float stdv = sqrtf(red[0] * (1.0f / 255.0f));
    out[i] = d / stdv;
}

extern "C" void kernel_launch(void* const* d_in, const int* in_sizes, int n_in,
                              void* d_out, int out_size, void* d_ws, size_t ws_size,
                              hipStream_t stream) {
    const float* img = (const float*)d_in[0];
    unsigned* g_hist = (unsigned*)d_ws;   // NHIST * 256 * 4 = 8 KB scratch
    float* out = (float*)d_out;

    hipMemsetAsync(g_hist, 0, NHIST * 256 * sizeof(unsigned), stream);
    lbp_hist_kernel<<<NBLOCKS, 256, 0, stream>>>(img, g_hist);
    lbp_finalize<<<1, 256, 0, stream>>>(g_hist, out);
}